// Round 11
// baseline (617.509 us; speedup 1.0000x reference)
//
#include <hip/hip_runtime.h>
#include <hip/hip_bf16.h>
#include <math.h>

// HelicalGNNFrontend: 2-layer GATv2 (heads=1, self-loops, mean loop edge_attr)
// N=50000, E=800000, NODE_DIM=HID=128, EDGE_DIM=32.
//
// Round 11: R8-proven fused config (2-wide pipeline, plain launch_bounds(64),
// permuted ea_s, scalar s_load edge stream) + PACKED DUAL-FP32:
// eproj and GEMM inner loops rewritten with ext_vector float2 so LLVM emits
// v_pk_fma_f32 (2 FMA/instr on CDNA4) -> ~halves VALU instruction count.
// Keep: fat1 (scatter+lin1 overlap), composed layer-1 weights, hierarchical
// scan, self-loop-last fold, defer-max.

#define HIP_N 50000
#define HIP_E 800000
#define HIP_H 128
#define HIP_ED 32
#define NEG_SLOPE 0.2f
#define RESCALE_THR 8.0f
#define LINB ((HIP_N + 31) / 32)          // 1563 lin blocks
#define SCATB ((HIP_E + 255) / 256)       // 3125 scatter blocks

typedef float v2f __attribute__((ext_vector_type(2)));
__device__ __forceinline__ v2f bc(float s) { v2f r; r.x = s; r.y = s; return r; }

// ---------------- edge-index dtype detection ----------------
__global__ void k_detect(const int* __restrict__ ei, int* __restrict__ is32) {
    int j = blockIdx.x * blockDim.x + threadIdx.x;   // j in [0, 4096)
    if (j < 4096) {
        if (ei[2 * j + 1] != 0) atomicOr(is32, 1);
    }
}

__device__ __forceinline__ int fetch_idx(const int* __restrict__ ei, int is32, long long pos) {
    return is32 ? ei[pos] : ei[2 * pos];  // little-endian low word for int64
}

// ---------------- CSR build ----------------
__global__ void k_hist(const int* __restrict__ ei, const int* __restrict__ flag,
                       int* __restrict__ deg) {
    int is32 = *flag;
    int e = blockIdx.x * blockDim.x + threadIdx.x;
    if (e < HIP_E) {
        int d = fetch_idx(ei, is32, (long long)HIP_E + e);
        atomicAdd(&deg[d], 1);
    }
}

#define SCAN_TILE 1024
#define SCAN_NB ((HIP_N + SCAN_TILE - 1) / SCAN_TILE)   // 49

__global__ __launch_bounds__(256) void k_scan1(const int* __restrict__ deg,
                                               int* __restrict__ bsums) {
    __shared__ int ws[4];
    int b = blockIdx.x, t = threadIdx.x;
    int base = b * SCAN_TILE;
    int v = 0;
#pragma unroll
    for (int j = 0; j < 4; ++j) {
        int i = base + t + 256 * j;
        if (i < HIP_N) v += deg[i];
    }
#pragma unroll
    for (int off = 32; off > 0; off >>= 1) v += __shfl_xor(v, off);
    int lane = t & 63, wid = t >> 6;
    if (lane == 0) ws[wid] = v;
    __syncthreads();
    if (t == 0) bsums[b] = ws[0] + ws[1] + ws[2] + ws[3];
}

__global__ __launch_bounds__(64) void k_scan2(const int* __restrict__ bsums,
                                              int* __restrict__ bscan) {
    int t = threadIdx.x;
    int v = (t < SCAN_NB) ? bsums[t] : 0;
    int incl = v;
#pragma unroll
    for (int off = 1; off < 64; off <<= 1) {
        int u = __shfl_up(incl, off);
        if (t >= off) incl += u;
    }
    if (t < SCAN_NB) bscan[t] = incl - v;   // exclusive
}

__global__ __launch_bounds__(1024) void k_scan3(const int* __restrict__ deg,
                                                const int* __restrict__ bscan,
                                                int* __restrict__ offs,
                                                int* __restrict__ cursor) {
    __shared__ int wsum[16];
    int b = blockIdx.x, t = threadIdx.x;
    int i = b * SCAN_TILE + t;
    int lane = t & 63, wid = t >> 6;
    int v = (i < HIP_N) ? deg[i] : 0;
    int incl = v;
#pragma unroll
    for (int off = 1; off < 64; off <<= 1) {
        int u = __shfl_up(incl, off);
        if (lane >= off) incl += u;
    }
    if (lane == 63) wsum[wid] = incl;
    __syncthreads();
    if (wid == 0 && lane < 16) {
        int w = wsum[lane];
#pragma unroll
        for (int off = 1; off < 16; off <<= 1) {
            int u = __shfl_up(w, off);
            if (lane >= off) w += u;
        }
        wsum[lane] = w;   // inclusive over waves
    }
    __syncthreads();
    int baseadd = bscan[b] + (wid > 0 ? wsum[wid - 1] : 0);
    int excl = baseadd + incl - v;
    if (i < HIP_N) {
        offs[i] = excl;
        cursor[i] = excl;
        if (i == HIP_N - 1) offs[HIP_N] = excl + v;
    }
}

// ---------------- shared bodies ----------------
// dual GEMM body with packed fp32: acc[r] = (accl, accr) in one v2f.
__device__ __forceinline__ void lin_body(const float* __restrict__ h,
                                         const float* __restrict__ Wl,
                                         const float* __restrict__ bl,
                                         const float* __restrict__ Wr,
                                         const float* __restrict__ br,
                                         float* __restrict__ xl,
                                         float* __restrict__ xr, int n, int blk) {
    __shared__ float tile[32][128];
    int rb = blk * 32;
    int tid = threadIdx.x;
    for (int j = 0; j < 16; ++j) {
        int idx = j * 256 + tid;
        int r = idx >> 7, c = idx & 127;
        int row = rb + r;
        tile[r][c] = (row < n) ? h[(size_t)row * 128 + c] : 0.f;
    }
    __syncthreads();
    int c = tid & 127, g = tid >> 7;
    v2f acc[16];
#pragma unroll
    for (int r = 0; r < 16; ++r) acc[r] = bc(0.f);
    for (int d4 = 0; d4 < 32; ++d4) {
        int d = d4 * 4;
        v2f wv0, wv1, wv2, wv3;
        wv0.x = Wl[(d + 0) * 128 + c]; wv0.y = Wr[(d + 0) * 128 + c];
        wv1.x = Wl[(d + 1) * 128 + c]; wv1.y = Wr[(d + 1) * 128 + c];
        wv2.x = Wl[(d + 2) * 128 + c]; wv2.y = Wr[(d + 2) * 128 + c];
        wv3.x = Wl[(d + 3) * 128 + c]; wv3.y = Wr[(d + 3) * 128 + c];
#pragma unroll
        for (int r = 0; r < 16; ++r) {
            const float4 hv = *(const float4*)&tile[g * 16 + r][d];
            acc[r] += bc(hv.x) * wv0;      // v_pk_fma_f32
            acc[r] += bc(hv.y) * wv1;
            acc[r] += bc(hv.z) * wv2;
            acc[r] += bc(hv.w) * wv3;
        }
    }
    float bbl = bl[c], bbr = br[c];
    for (int r = 0; r < 16; ++r) {
        int row = rb + g * 16 + r;
        if (row < n) {
            xl[(size_t)row * 128 + c] = acc[r].x + bbl;
            xr[(size_t)row * 128 + c] = acc[r].y + bbr;
        }
    }
}

// scatter body: e_src[pos]=src, ea_s[pos]=ea[e] (permuted rows, R8-proven)
__device__ __forceinline__ void scatter_body(const int* __restrict__ ei, int is32,
                                             int* __restrict__ cursor,
                                             int* __restrict__ e_src,
                                             const float* __restrict__ ea,
                                             float* __restrict__ ea_s, int e) {
    if (e < HIP_E) {
        int s = fetch_idx(ei, is32, e);
        int d = fetch_idx(ei, is32, (long long)HIP_E + e);
        int pos = atomicAdd(&cursor[d], 1);
        e_src[pos] = s;
        const float4* src4 = (const float4*)(ea + (size_t)e * HIP_ED);
        float4* dst4 = (float4*)(ea_s + (size_t)pos * HIP_ED);
#pragma unroll
        for (int q = 0; q < 8; ++q) dst4[q] = src4[q];
    }
}

// fat kernel: blocks [0, LINB) do layer-1 lin; blocks [LINB, LINB+SCATB) scatter
__global__ __launch_bounds__(256) void k_fat1(
    const float* __restrict__ x, const float* __restrict__ Wl,
    const float* __restrict__ bl, const float* __restrict__ Wr,
    const float* __restrict__ br, float* __restrict__ xl, float* __restrict__ xr,
    const int* __restrict__ ei, const int* __restrict__ flag,
    int* __restrict__ cursor, int* __restrict__ e_src,
    const float* __restrict__ ea, float* __restrict__ ea_s) {
    if (blockIdx.x < LINB) {
        lin_body(x, Wl, bl, Wr, br, xl, xr, HIP_N, blockIdx.x);
    } else {
        int e = (blockIdx.x - LINB) * 256 + threadIdx.x;
        scatter_body(ei, *flag, cursor, e_src, ea, ea_s, e);
    }
}

__global__ __launch_bounds__(256) void k_lin(const float* __restrict__ h,
                                             const float* __restrict__ Wl,
                                             const float* __restrict__ bl,
                                             const float* __restrict__ Wr,
                                             const float* __restrict__ br,
                                             float* __restrict__ xl,
                                             float* __restrict__ xr, int n) {
    lin_body(h, Wl, bl, Wr, br, xl, xr, n, blockIdx.x);
}

// ---------------- weight composition (folds k_emb into layer-1) ----------------
__global__ __launch_bounds__(128) void k_compose(
    const float* __restrict__ Wemb, const float* __restrict__ bemb,
    const float* __restrict__ Wl, const float* __restrict__ bl,
    const float* __restrict__ Wr,
    float* __restrict__ Wlf, float* __restrict__ blf,
    float* __restrict__ Wrf, float* __restrict__ brf,
    float* __restrict__ zerob) {
    int b = blockIdx.x, c = threadIdx.x;
    if (b < 128) {
        float acc = 0.f;
        for (int k = 0; k < 128; ++k) acc += Wemb[b * 128 + k] * Wl[k * 128 + c];
        Wlf[b * 128 + c] = acc;
    } else if (b < 256) {
        int r = b - 128;
        float acc = 0.f;
        for (int k = 0; k < 128; ++k) acc += Wemb[r * 128 + k] * Wr[k * 128 + c];
        Wrf[r * 128 + c] = acc;
    } else if (b == 256) {
        float acc = bl[c];
        for (int k = 0; k < 128; ++k) acc += bemb[k] * Wl[k * 128 + c];
        blf[c] = acc;
    } else {
        float acc = 0.f;
        for (int k = 0; k < 128; ++k) acc += bemb[k] * Wr[k * 128 + c];
        brf[c] = acc;
        zerob[c] = 0.f;
    }
}

// ---------------- fused per-node online softmax + aggregation ----------------
// ONE 64-thread block per node. All per-edge addresses wave-uniform -> scalar
// s_load path; only the xl gather uses vector memory. eproj uses packed
// v_pk_fma_f32 (both feature dims per instruction). 2-wide edge pipeline.
__global__ __launch_bounds__(64) void k_node_fused(
    const int* __restrict__ offs, const int* __restrict__ e_src,
    const float* __restrict__ ea_s,
    const float* __restrict__ We, const float* __restrict__ att,
    const float* __restrict__ xl, const float* __restrict__ xr,
    const float* __restrict__ bo, float* __restrict__ hout) {
    int i = blockIdx.x;           // uniform node id
    int t = threadIdx.x;          // lane, owns feature dims (2t, 2t+1)

    const v2f* We2 = (const v2f*)We;
    v2f w00 = We2[ 0*64+t], w01 = We2[ 1*64+t], w02 = We2[ 2*64+t], w03 = We2[ 3*64+t];
    v2f w04 = We2[ 4*64+t], w05 = We2[ 5*64+t], w06 = We2[ 6*64+t], w07 = We2[ 7*64+t];
    v2f w08 = We2[ 8*64+t], w09 = We2[ 9*64+t], w10 = We2[10*64+t], w11 = We2[11*64+t];
    v2f w12 = We2[12*64+t], w13 = We2[13*64+t], w14 = We2[14*64+t], w15 = We2[15*64+t];
    v2f w16 = We2[16*64+t], w17 = We2[17*64+t], w18 = We2[18*64+t], w19 = We2[19*64+t];
    v2f w20 = We2[20*64+t], w21 = We2[21*64+t], w22 = We2[22*64+t], w23 = We2[23*64+t];
    v2f w24 = We2[24*64+t], w25 = We2[25*64+t], w26 = We2[26*64+t], w27 = We2[27*64+t];
    v2f w28 = We2[28*64+t], w29 = We2[29*64+t], w30 = We2[30*64+t], w31 = We2[31*64+t];

    v2f attv = ((const v2f*)att)[t];
    v2f bov  = ((const v2f*)bo)[t];
    v2f xri  = ((const v2f*)(xr + (size_t)i * HIP_H))[t];
    v2f xli  = ((const v2f*)(xl + (size_t)i * HIP_H))[t];

    float m = -1e30f;
    float denom = 0.f;
    v2f accv = bc(0.f);
    v2f epsv = bc(0.f);             // sum of per-edge eproj (for self-loop)

    int o0 = offs[i], o1 = offs[i + 1];     // uniform -> s_load
    int cnt = o1 - o0;
    int pairs = cnt >> 1;
    const v2f* xl2 = (const v2f*)xl;

#define EPROJ(ACC, P)                                                 \
    {                                                                 \
        float4 a0 = (P)[0], a1 = (P)[1], a2 = (P)[2], a3 = (P)[3];    \
        float4 a4 = (P)[4], a5 = (P)[5], a6 = (P)[6], a7 = (P)[7];    \
        ACC += bc(a0.x) * w00; ACC += bc(a0.y) * w01;                 \
        ACC += bc(a0.z) * w02; ACC += bc(a0.w) * w03;                 \
        ACC += bc(a1.x) * w04; ACC += bc(a1.y) * w05;                 \
        ACC += bc(a1.z) * w06; ACC += bc(a1.w) * w07;                 \
        ACC += bc(a2.x) * w08; ACC += bc(a2.y) * w09;                 \
        ACC += bc(a2.z) * w10; ACC += bc(a2.w) * w11;                 \
        ACC += bc(a3.x) * w12; ACC += bc(a3.y) * w13;                 \
        ACC += bc(a3.z) * w14; ACC += bc(a3.w) * w15;                 \
        ACC += bc(a4.x) * w16; ACC += bc(a4.y) * w17;                 \
        ACC += bc(a4.z) * w18; ACC += bc(a4.w) * w19;                 \
        ACC += bc(a5.x) * w20; ACC += bc(a5.y) * w21;                 \
        ACC += bc(a5.z) * w22; ACC += bc(a5.w) * w23;                 \
        ACC += bc(a6.x) * w24; ACC += bc(a6.y) * w25;                 \
        ACC += bc(a6.z) * w26; ACC += bc(a6.w) * w27;                 \
        ACC += bc(a7.x) * w28; ACC += bc(a7.y) * w29;                 \
        ACC += bc(a7.z) * w30; ACC += bc(a7.w) * w31;                 \
    }

    // pair-ahead prefetch of the two xl gathers
    v2f xA = bc(0.f), xB = bc(0.f);
    if (pairs > 0) {
        int s0 = e_src[o0];                 // uniform -> s_load
        int s1 = e_src[o0 + 1];
        xA = xl2[(size_t)s0 * 64 + t];
        xB = xl2[(size_t)s1 * 64 + t];
    }

    for (int pp = 0; pp < pairs; ++pp) {
        int e = o0 + 2 * pp;
        v2f x0 = xA, x1 = xB;
        if (pp + 1 < pairs) {               // prefetch next pair's gathers
            int s0 = e_src[e + 2];
            int s1 = e_src[e + 3];
            xA = xl2[(size_t)s0 * 64 + t];
            xB = xl2[(size_t)s1 * 64 + t];
        }
        const float4* ea4 = (const float4*)(ea_s + (size_t)e * HIP_ED);  // uniform
        v2f ep0 = bc(0.f), ep1 = bc(0.f);
        EPROJ(ep0, ea4)
        EPROJ(ep1, ea4 + 8)
        epsv += ep0 + ep1;
        v2f v0 = x0 + xri + ep0;
        v2f v1 = x1 + xri + ep1;
        float vx0 = v0.x > 0.f ? v0.x : NEG_SLOPE * v0.x;
        float vy0 = v0.y > 0.f ? v0.y : NEG_SLOPE * v0.y;
        float vx1 = v1.x > 0.f ? v1.x : NEG_SLOPE * v1.x;
        float vy1 = v1.y > 0.f ? v1.y : NEG_SLOPE * v1.y;
        float p0 = vx0 * attv.x + vy0 * attv.y;
        float p1 = vx1 * attv.x + vy1 * attv.y;
#pragma unroll
        for (int off = 32; off > 0; off >>= 1) {   // interleaved chains
            p0 += __shfl_xor(p0, off);
            p1 += __shfl_xor(p1, off);
        }
        float pm = fmaxf(p0, p1);
        if (pm > m + RESCALE_THR) {         // defer-max rescale (wave-uniform)
            float sc = __expf(m - pm);
            accv *= bc(sc); denom *= sc;
            m = pm;
        }
        float wA = __expf(p0 - m);
        float wB = __expf(p1 - m);
        accv += bc(wA) * x0;
        accv += bc(wB) * x1;
        denom += wA + wB;
    }

    if (cnt & 1) {                          // tail edge
        int e = o1 - 1;
        int s = e_src[e];
        v2f x0 = xl2[(size_t)s * 64 + t];
        const float4* ea4 = (const float4*)(ea_s + (size_t)e * HIP_ED);
        v2f ep = bc(0.f);
        EPROJ(ep, ea4)
        epsv += ep;
        v2f v0 = x0 + xri + ep;
        float vx = v0.x > 0.f ? v0.x : NEG_SLOPE * v0.x;
        float vy = v0.y > 0.f ? v0.y : NEG_SLOPE * v0.y;
        float p = vx * attv.x + vy * attv.y;
#pragma unroll
        for (int off = 32; off > 0; off >>= 1) p += __shfl_xor(p, off);
        if (p > m + RESCALE_THR) {
            float sc = __expf(m - p);
            accv *= bc(sc); denom *= sc;
            m = p;
        }
        float w = __expf(p - m);
        accv += bc(w) * x0;
        denom += w;
    }
#undef EPROJ

    // ---- self-loop (last): loop_attr projection = mean of eproj ----
    float invdeg = 1.f / fmaxf((float)cnt, 1.f);
    v2f sv = xli + xri + epsv * bc(invdeg);
    float sx = sv.x > 0.f ? sv.x : NEG_SLOPE * sv.x;
    float sy = sv.y > 0.f ? sv.y : NEG_SLOPE * sv.y;
    float ps = sx * attv.x + sy * attv.y;
#pragma unroll
    for (int off = 32; off > 0; off >>= 1) ps += __shfl_xor(ps, off);

    float mm = fmaxf(m, ps);
    float wf = __expf(m - mm);
    float ws = __expf(ps - mm);
    denom = denom * wf + ws;
    accv = accv * bc(wf) + bc(ws) * xli;

    float ox = accv.x / denom + bov.x;
    float oy = accv.y / denom + bov.y;
    v2f o;
    o.x = ox / (1.f + __expf(-ox));
    o.y = oy / (1.f + __expf(-oy));
    ((v2f*)(hout + (size_t)i * HIP_H))[t] = o;
}

// ---------------- host launch ----------------
extern "C" void kernel_launch(void* const* d_in, const int* in_sizes, int n_in,
                              void* d_out, int out_size, void* d_ws, size_t ws_size,
                              hipStream_t stream) {
    const float* x      = (const float*)d_in[0];
    const int*   ei     = (const int*)d_in[1];
    const float* ea     = (const float*)d_in[2];
    const float* W_emb  = (const float*)d_in[3];
    const float* b_emb  = (const float*)d_in[4];
    const float* Wl1    = (const float*)d_in[5];
    const float* bl1    = (const float*)d_in[6];
    const float* Wr1    = (const float*)d_in[7];
    const float* We1    = (const float*)d_in[8];
    const float* att1   = (const float*)d_in[9];
    const float* bo1    = (const float*)d_in[10];
    const float* Wl2    = (const float*)d_in[11];
    const float* bl2    = (const float*)d_in[12];
    const float* Wr2    = (const float*)d_in[13];
    const float* We2    = (const float*)d_in[14];
    const float* att2   = (const float*)d_in[15];
    const float* bo2    = (const float*)d_in[16];
    float* out = (float*)d_out;

    char* p = (char*)d_ws;
    auto carve = [&](size_t bytes) {
        void* q = (void*)p;
        p += (bytes + 255) / 256 * 256;
        return q;
    };
    float* h        = (float*)carve((size_t)HIP_N * 128 * 4);
    float* xl       = (float*)carve((size_t)HIP_N * 128 * 4);
    float* xr       = (float*)carve((size_t)HIP_N * 128 * 4);
    float* ea_s     = (float*)carve((size_t)HIP_E * HIP_ED * 4);
    int*   deg      = (int*)carve((size_t)HIP_N * 4);
    int*   offs     = (int*)carve((size_t)(HIP_N + 1) * 4);
    int*   cursor   = (int*)carve((size_t)HIP_N * 4);
    int*   e_src    = (int*)carve((size_t)HIP_E * 4);
    int*   flag     = (int*)carve(256);
    int*   bsums    = (int*)carve((size_t)SCAN_NB * 4);
    int*   bscan    = (int*)carve((size_t)SCAN_NB * 4);
    float* Wl1f     = (float*)carve(128 * 128 * 4);
    float* Wr1f     = (float*)carve(128 * 128 * 4);
    float* bl1f     = (float*)carve(128 * 4);
    float* br1f     = (float*)carve(128 * 4);
    float* zerob    = (float*)carve(128 * 4);

    hipMemsetAsync(deg, 0, (size_t)HIP_N * 4, stream);
    hipMemsetAsync(flag, 0, 4, stream);

    k_detect<<<16, 256, 0, stream>>>(ei, flag);
    k_hist<<<(HIP_E + 255) / 256, 256, 0, stream>>>(ei, flag, deg);
    k_scan1<<<SCAN_NB, 256, 0, stream>>>(deg, bsums);
    k_scan2<<<1, 64, 0, stream>>>(bsums, bscan);
    k_scan3<<<SCAN_NB, 1024, 0, stream>>>(deg, bscan, offs, cursor);
    k_compose<<<258, 128, 0, stream>>>(W_emb, b_emb, Wl1, bl1, Wr1,
                                       Wl1f, bl1f, Wr1f, br1f, zerob);

    // fat dispatch: layer-1 lin (composed weights, input x) + CSR scatter
    k_fat1<<<LINB + SCATB, 256, 0, stream>>>(x, Wl1f, bl1f, Wr1f, br1f, xl, xr,
                                             ei, flag, cursor, e_src, ea, ea_s);

    // ----- layer 1 -----
    k_node_fused<<<HIP_N, 64, 0, stream>>>(offs, e_src, ea_s, We1, att1,
                                           xl, xr, bo1, h);
    // ----- layer 2 -----
    k_lin<<<(HIP_N + 31) / 32, 256, 0, stream>>>(h, Wl2, bl2, Wr2, zerob, xl, xr, HIP_N);
    k_node_fused<<<HIP_N, 64, 0, stream>>>(offs, e_src, ea_s, We2, att2,
                                           xl, xr, bo2, out);
}

// Round 13
// 496.869 us; speedup vs baseline: 1.2428x; 1.2428x over previous
//
#include <hip/hip_runtime.h>
#include <hip/hip_bf16.h>
#include <math.h>

// HelicalGNNFrontend: 2-layer GATv2 (heads=1, self-loops, mean loop edge_attr)
// N=50000, E=800000, NODE_DIM=HID=128, EDGE_DIM=32.
//
// Round 12b: same as R12 (f16 v_dot2 eproj) with the h2 typedef fixed to
// __fp16 (cvt_pkrtz returns a __fp16 ext-vector; fdot2's signature is V2h).
//   - We pre-packed to half2 pairs-over-d (k_packwe), held in 32 VGPRs
//   - ea_s stored as half2 by the scatter (halves scatter + SMEM traffic)
//   - 32 fdot2/edge instead of 64 FMA (SGPR operand legal in VOP3P dot)
// Precision: f16 in, fp32 accumulate; harness threshold 8e-3 (bf16-floored).

#define HIP_N 50000
#define HIP_E 800000
#define HIP_H 128
#define HIP_ED 32
#define NEG_SLOPE 0.2f
#define RESCALE_THR 8.0f
#define LINB ((HIP_N + 31) / 32)          // 1563 lin blocks
#define SCATB ((HIP_E + 255) / 256)       // 3125 scatter blocks

typedef __fp16 h2 __attribute__((ext_vector_type(2)));

__device__ __forceinline__ h2 u2h(unsigned int u) {
    union { unsigned int u; h2 h; } c; c.u = u; return c.h;
}
__device__ __forceinline__ unsigned int pkh(float a, float b) {
    union { h2 h; unsigned int u; } c;
    c.h = __builtin_amdgcn_cvt_pkrtz(a, b);
    return c.u;
}

// ---------------- edge-index dtype detection ----------------
__global__ void k_detect(const int* __restrict__ ei, int* __restrict__ is32) {
    int j = blockIdx.x * blockDim.x + threadIdx.x;   // j in [0, 4096)
    if (j < 4096) {
        if (ei[2 * j + 1] != 0) atomicOr(is32, 1);
    }
}

__device__ __forceinline__ int fetch_idx(const int* __restrict__ ei, int is32, long long pos) {
    return is32 ? ei[pos] : ei[2 * pos];  // little-endian low word for int64
}

// ---------------- CSR build ----------------
__global__ void k_hist(const int* __restrict__ ei, const int* __restrict__ flag,
                       int* __restrict__ deg) {
    int is32 = *flag;
    int e = blockIdx.x * blockDim.x + threadIdx.x;
    if (e < HIP_E) {
        int d = fetch_idx(ei, is32, (long long)HIP_E + e);
        atomicAdd(&deg[d], 1);
    }
}

#define SCAN_TILE 1024
#define SCAN_NB ((HIP_N + SCAN_TILE - 1) / SCAN_TILE)   // 49

__global__ __launch_bounds__(256) void k_scan1(const int* __restrict__ deg,
                                               int* __restrict__ bsums) {
    __shared__ int ws[4];
    int b = blockIdx.x, t = threadIdx.x;
    int base = b * SCAN_TILE;
    int v = 0;
#pragma unroll
    for (int j = 0; j < 4; ++j) {
        int i = base + t + 256 * j;
        if (i < HIP_N) v += deg[i];
    }
#pragma unroll
    for (int off = 32; off > 0; off >>= 1) v += __shfl_xor(v, off);
    int lane = t & 63, wid = t >> 6;
    if (lane == 0) ws[wid] = v;
    __syncthreads();
    if (t == 0) bsums[b] = ws[0] + ws[1] + ws[2] + ws[3];
}

__global__ __launch_bounds__(64) void k_scan2(const int* __restrict__ bsums,
                                              int* __restrict__ bscan) {
    int t = threadIdx.x;
    int v = (t < SCAN_NB) ? bsums[t] : 0;
    int incl = v;
#pragma unroll
    for (int off = 1; off < 64; off <<= 1) {
        int u = __shfl_up(incl, off);
        if (t >= off) incl += u;
    }
    if (t < SCAN_NB) bscan[t] = incl - v;   // exclusive
}

__global__ __launch_bounds__(1024) void k_scan3(const int* __restrict__ deg,
                                                const int* __restrict__ bscan,
                                                int* __restrict__ offs,
                                                int* __restrict__ cursor) {
    __shared__ int wsum[16];
    int b = blockIdx.x, t = threadIdx.x;
    int i = b * SCAN_TILE + t;
    int lane = t & 63, wid = t >> 6;
    int v = (i < HIP_N) ? deg[i] : 0;
    int incl = v;
#pragma unroll
    for (int off = 1; off < 64; off <<= 1) {
        int u = __shfl_up(incl, off);
        if (lane >= off) incl += u;
    }
    if (lane == 63) wsum[wid] = incl;
    __syncthreads();
    if (wid == 0 && lane < 16) {
        int w = wsum[lane];
#pragma unroll
        for (int off = 1; off < 16; off <<= 1) {
            int u = __shfl_up(w, off);
            if (lane >= off) w += u;
        }
        wsum[lane] = w;   // inclusive over waves
    }
    __syncthreads();
    int baseadd = bscan[b] + (wid > 0 ? wsum[wid - 1] : 0);
    int excl = baseadd + incl - v;
    if (i < HIP_N) {
        offs[i] = excl;
        cursor[i] = excl;
        if (i == HIP_N - 1) offs[HIP_N] = excl + v;
    }
}

// ---------------- shared bodies ----------------
// dual GEMM body (R8-proven scalar form)
__device__ __forceinline__ void lin_body(const float* __restrict__ h,
                                         const float* __restrict__ Wl,
                                         const float* __restrict__ bl,
                                         const float* __restrict__ Wr,
                                         const float* __restrict__ br,
                                         float* __restrict__ xl,
                                         float* __restrict__ xr, int n, int blk) {
    __shared__ float tile[32][128];
    int rb = blk * 32;
    int tid = threadIdx.x;
    for (int j = 0; j < 16; ++j) {
        int idx = j * 256 + tid;
        int r = idx >> 7, c = idx & 127;
        int row = rb + r;
        tile[r][c] = (row < n) ? h[(size_t)row * 128 + c] : 0.f;
    }
    __syncthreads();
    int c = tid & 127, g = tid >> 7;
    float accl[16], accr[16];
#pragma unroll
    for (int r = 0; r < 16; ++r) { accl[r] = 0.f; accr[r] = 0.f; }
    for (int d4 = 0; d4 < 32; ++d4) {
        int d = d4 * 4;
        float wl0 = Wl[(d + 0) * 128 + c];
        float wl1 = Wl[(d + 1) * 128 + c];
        float wl2 = Wl[(d + 2) * 128 + c];
        float wl3 = Wl[(d + 3) * 128 + c];
        float wr0 = Wr[(d + 0) * 128 + c];
        float wr1 = Wr[(d + 1) * 128 + c];
        float wr2 = Wr[(d + 2) * 128 + c];
        float wr3 = Wr[(d + 3) * 128 + c];
#pragma unroll
        for (int r = 0; r < 16; ++r) {
            const float4 hv = *(const float4*)&tile[g * 16 + r][d];
            accl[r] += hv.x * wl0 + hv.y * wl1 + hv.z * wl2 + hv.w * wl3;
            accr[r] += hv.x * wr0 + hv.y * wr1 + hv.z * wr2 + hv.w * wr3;
        }
    }
    float bbl = bl[c], bbr = br[c];
    for (int r = 0; r < 16; ++r) {
        int row = rb + g * 16 + r;
        if (row < n) {
            xl[(size_t)row * 128 + c] = accl[r] + bbl;
            xr[(size_t)row * 128 + c] = accr[r] + bbr;
        }
    }
}

// scatter body: e_src[pos]=src, ea_h[pos]= half2-packed ea row (64B)
__device__ __forceinline__ void scatter_body(const int* __restrict__ ei, int is32,
                                             int* __restrict__ cursor,
                                             int* __restrict__ e_src,
                                             const float* __restrict__ ea,
                                             unsigned int* __restrict__ ea_h, int e) {
    if (e < HIP_E) {
        int s = fetch_idx(ei, is32, e);
        int d = fetch_idx(ei, is32, (long long)HIP_E + e);
        int pos = atomicAdd(&cursor[d], 1);
        e_src[pos] = s;
        const float4* src4 = (const float4*)(ea + (size_t)e * HIP_ED);
        float4 s0 = src4[0], s1 = src4[1], s2 = src4[2], s3 = src4[3];
        float4 s4 = src4[4], s5 = src4[5], s6 = src4[6], s7 = src4[7];
        uint4* dst = (uint4*)(ea_h + (size_t)pos * 16);
        dst[0] = make_uint4(pkh(s0.x, s0.y), pkh(s0.z, s0.w),
                            pkh(s1.x, s1.y), pkh(s1.z, s1.w));
        dst[1] = make_uint4(pkh(s2.x, s2.y), pkh(s2.z, s2.w),
                            pkh(s3.x, s3.y), pkh(s3.z, s3.w));
        dst[2] = make_uint4(pkh(s4.x, s4.y), pkh(s4.z, s4.w),
                            pkh(s5.x, s5.y), pkh(s5.z, s5.w));
        dst[3] = make_uint4(pkh(s6.x, s6.y), pkh(s6.z, s6.w),
                            pkh(s7.x, s7.y), pkh(s7.z, s7.w));
    }
}

// fat kernel: blocks [0, LINB) do layer-1 lin; blocks [LINB, LINB+SCATB) scatter
__global__ __launch_bounds__(256) void k_fat1(
    const float* __restrict__ x, const float* __restrict__ Wl,
    const float* __restrict__ bl, const float* __restrict__ Wr,
    const float* __restrict__ br, float* __restrict__ xl, float* __restrict__ xr,
    const int* __restrict__ ei, const int* __restrict__ flag,
    int* __restrict__ cursor, int* __restrict__ e_src,
    const float* __restrict__ ea, unsigned int* __restrict__ ea_h) {
    if (blockIdx.x < LINB) {
        lin_body(x, Wl, bl, Wr, br, xl, xr, HIP_N, blockIdx.x);
    } else {
        int e = (blockIdx.x - LINB) * 256 + threadIdx.x;
        scatter_body(ei, *flag, cursor, e_src, ea, ea_h, e);
    }
}

__global__ __launch_bounds__(256) void k_lin(const float* __restrict__ h,
                                             const float* __restrict__ Wl,
                                             const float* __restrict__ bl,
                                             const float* __restrict__ Wr,
                                             const float* __restrict__ br,
                                             float* __restrict__ xl,
                                             float* __restrict__ xr, int n) {
    lin_body(h, Wl, bl, Wr, br, xl, xr, n, blockIdx.x);
}

// ---------------- weight composition (folds k_emb into layer-1) ----------------
__global__ __launch_bounds__(128) void k_compose(
    const float* __restrict__ Wemb, const float* __restrict__ bemb,
    const float* __restrict__ Wl, const float* __restrict__ bl,
    const float* __restrict__ Wr,
    float* __restrict__ Wlf, float* __restrict__ blf,
    float* __restrict__ Wrf, float* __restrict__ brf,
    float* __restrict__ zerob) {
    int b = blockIdx.x, c = threadIdx.x;
    if (b < 128) {
        float acc = 0.f;
        for (int k = 0; k < 128; ++k) acc += Wemb[b * 128 + k] * Wl[k * 128 + c];
        Wlf[b * 128 + c] = acc;
    } else if (b < 256) {
        int r = b - 128;
        float acc = 0.f;
        for (int k = 0; k < 128; ++k) acc += Wemb[r * 128 + k] * Wr[k * 128 + c];
        Wrf[r * 128 + c] = acc;
    } else if (b == 256) {
        float acc = bl[c];
        for (int k = 0; k < 128; ++k) acc += bemb[k] * Wl[k * 128 + c];
        blf[c] = acc;
    } else {
        float acc = 0.f;
        for (int k = 0; k < 128; ++k) acc += bemb[k] * Wr[k * 128 + c];
        brf[c] = acc;
        zerob[c] = 0.f;
    }
}

// pack We (32x128 fp32) -> Wepk (2048 uint: half2 over d-pairs)
// Wepk[d2*128 + j*64 + t] = half2(We[2*d2][2*t+j], We[2*d2+1][2*t+j])
__global__ __launch_bounds__(256) void k_packwe(const float* __restrict__ We1,
                                                const float* __restrict__ We2,
                                                unsigned int* __restrict__ P1,
                                                unsigned int* __restrict__ P2) {
    int idx = blockIdx.x * 256 + threadIdx.x;     // [0, 4096)
    if (idx < 4096) {
        const float* We = (idx < 2048) ? We1 : We2;
        unsigned int* P = (idx < 2048) ? P1 : P2;
        int r = idx & 2047;
        int d2 = r >> 7, rem = r & 127;
        int j = rem >> 6, t = rem & 63;
        int col = 2 * t + j;
        P[r] = pkh(We[(2 * d2) * 128 + col], We[(2 * d2 + 1) * 128 + col]);
    }
}

// ---------------- fused per-node online softmax + aggregation ----------------
// ONE 64-thread block per node. Per-edge addresses wave-uniform -> s_load;
// only the xl gather on vector memory. eproj: 32x fdot2 (f16 pairs, fp32 acc),
// ea pair comes from SGPR, We pair from VGPR. 2-wide edge pipeline.
__global__ __launch_bounds__(64) void k_node_fused(
    const int* __restrict__ offs, const int* __restrict__ e_src,
    const unsigned int* __restrict__ ea_h,
    const unsigned int* __restrict__ Wepk, const float* __restrict__ att,
    const float* __restrict__ xl, const float* __restrict__ xr,
    const float* __restrict__ bo, float* __restrict__ hout) {
    int i = blockIdx.x;           // uniform node id
    int t = threadIdx.x;          // lane, owns feature dims (2t, 2t+1)

    // We pairs: wxK = (We[2K][2t], We[2K+1][2t]), wyK = same for dim 2t+1
    h2 wx00 = u2h(Wepk[ 0*128 + t]),      wy00 = u2h(Wepk[ 0*128 + 64 + t]);
    h2 wx01 = u2h(Wepk[ 1*128 + t]),      wy01 = u2h(Wepk[ 1*128 + 64 + t]);
    h2 wx02 = u2h(Wepk[ 2*128 + t]),      wy02 = u2h(Wepk[ 2*128 + 64 + t]);
    h2 wx03 = u2h(Wepk[ 3*128 + t]),      wy03 = u2h(Wepk[ 3*128 + 64 + t]);
    h2 wx04 = u2h(Wepk[ 4*128 + t]),      wy04 = u2h(Wepk[ 4*128 + 64 + t]);
    h2 wx05 = u2h(Wepk[ 5*128 + t]),      wy05 = u2h(Wepk[ 5*128 + 64 + t]);
    h2 wx06 = u2h(Wepk[ 6*128 + t]),      wy06 = u2h(Wepk[ 6*128 + 64 + t]);
    h2 wx07 = u2h(Wepk[ 7*128 + t]),      wy07 = u2h(Wepk[ 7*128 + 64 + t]);
    h2 wx08 = u2h(Wepk[ 8*128 + t]),      wy08 = u2h(Wepk[ 8*128 + 64 + t]);
    h2 wx09 = u2h(Wepk[ 9*128 + t]),      wy09 = u2h(Wepk[ 9*128 + 64 + t]);
    h2 wx10 = u2h(Wepk[10*128 + t]),      wy10 = u2h(Wepk[10*128 + 64 + t]);
    h2 wx11 = u2h(Wepk[11*128 + t]),      wy11 = u2h(Wepk[11*128 + 64 + t]);
    h2 wx12 = u2h(Wepk[12*128 + t]),      wy12 = u2h(Wepk[12*128 + 64 + t]);
    h2 wx13 = u2h(Wepk[13*128 + t]),      wy13 = u2h(Wepk[13*128 + 64 + t]);
    h2 wx14 = u2h(Wepk[14*128 + t]),      wy14 = u2h(Wepk[14*128 + 64 + t]);
    h2 wx15 = u2h(Wepk[15*128 + t]),      wy15 = u2h(Wepk[15*128 + 64 + t]);

    float2 attv = ((const float2*)att)[t];
    float2 bov  = ((const float2*)bo)[t];
    float2 xri  = ((const float2*)(xr + (size_t)i * HIP_H))[t];
    float2 xli  = ((const float2*)(xl + (size_t)i * HIP_H))[t];

    float m = -1e30f;
    float denom = 0.f;
    float accx = 0.f, accy = 0.f;
    float epsx = 0.f, epsy = 0.f;   // sum of per-edge eproj (for self-loop)

    int o0 = offs[i], o1 = offs[i + 1];     // uniform -> s_load
    int cnt = o1 - o0;
    int pairs = cnt >> 1;
    const float2* xl2 = (const float2*)xl;

#define DOTP(EX, EY, U, K)                                            \
    EX = __builtin_amdgcn_fdot2(u2h(U), wx##K, EX, false);            \
    EY = __builtin_amdgcn_fdot2(u2h(U), wy##K, EY, false);

#define EPROJ(EX, EY, P)                                              \
    {                                                                 \
        uint4 q0 = ((const uint4*)(P))[0];                            \
        uint4 q1 = ((const uint4*)(P))[1];                            \
        uint4 q2 = ((const uint4*)(P))[2];                            \
        uint4 q3 = ((const uint4*)(P))[3];                            \
        DOTP(EX, EY, q0.x, 00) DOTP(EX, EY, q0.y, 01)                 \
        DOTP(EX, EY, q0.z, 02) DOTP(EX, EY, q0.w, 03)                 \
        DOTP(EX, EY, q1.x, 04) DOTP(EX, EY, q1.y, 05)                 \
        DOTP(EX, EY, q1.z, 06) DOTP(EX, EY, q1.w, 07)                 \
        DOTP(EX, EY, q2.x, 08) DOTP(EX, EY, q2.y, 09)                 \
        DOTP(EX, EY, q2.z, 10) DOTP(EX, EY, q2.w, 11)                 \
        DOTP(EX, EY, q3.x, 12) DOTP(EX, EY, q3.y, 13)                 \
        DOTP(EX, EY, q3.z, 14) DOTP(EX, EY, q3.w, 15)                 \
    }

    // pair-ahead prefetch of the two xl gathers
    float2 xA = make_float2(0.f, 0.f), xB = make_float2(0.f, 0.f);
    if (pairs > 0) {
        int s0 = e_src[o0];                 // uniform -> s_load
        int s1 = e_src[o0 + 1];
        xA = xl2[(size_t)s0 * 64 + t];
        xB = xl2[(size_t)s1 * 64 + t];
    }

    for (int pp = 0; pp < pairs; ++pp) {
        int e = o0 + 2 * pp;
        float2 x0 = xA, x1 = xB;
        if (pp + 1 < pairs) {               // prefetch next pair's gathers
            int s0 = e_src[e + 2];
            int s1 = e_src[e + 3];
            xA = xl2[(size_t)s0 * 64 + t];
            xB = xl2[(size_t)s1 * 64 + t];
        }
        const unsigned int* er = ea_h + (size_t)e * 16;   // uniform (2 rows, 32 dw)
        float ex0 = 0.f, ey0 = 0.f, ex1 = 0.f, ey1 = 0.f;
        EPROJ(ex0, ey0, er)
        EPROJ(ex1, ey1, er + 16)
        epsx += ex0 + ex1; epsy += ey0 + ey1;
        float vx0 = x0.x + xri.x + ex0, vy0 = x0.y + xri.y + ey0;
        float vx1 = x1.x + xri.x + ex1, vy1 = x1.y + xri.y + ey1;
        vx0 = vx0 > 0.f ? vx0 : NEG_SLOPE * vx0;
        vy0 = vy0 > 0.f ? vy0 : NEG_SLOPE * vy0;
        vx1 = vx1 > 0.f ? vx1 : NEG_SLOPE * vx1;
        vy1 = vy1 > 0.f ? vy1 : NEG_SLOPE * vy1;
        float p0 = vx0 * attv.x + vy0 * attv.y;
        float p1 = vx1 * attv.x + vy1 * attv.y;
#pragma unroll
        for (int off = 32; off > 0; off >>= 1) {   // interleaved chains
            p0 += __shfl_xor(p0, off);
            p1 += __shfl_xor(p1, off);
        }
        float pm = fmaxf(p0, p1);
        if (pm > m + RESCALE_THR) {         // defer-max rescale (wave-uniform)
            float sc = __expf(m - pm);
            accx *= sc; accy *= sc; denom *= sc;
            m = pm;
        }
        float wA = __expf(p0 - m);
        float wB = __expf(p1 - m);
        accx += wA * x0.x + wB * x1.x;
        accy += wA * x0.y + wB * x1.y;
        denom += wA + wB;
    }

    if (cnt & 1) {                          // tail edge
        int e = o1 - 1;
        int s = e_src[e];
        float2 x0 = xl2[(size_t)s * 64 + t];
        const unsigned int* er = ea_h + (size_t)e * 16;
        float ex = 0.f, ey = 0.f;
        EPROJ(ex, ey, er)
        epsx += ex; epsy += ey;
        float vx = x0.x + xri.x + ex;
        float vy = x0.y + xri.y + ey;
        vx = vx > 0.f ? vx : NEG_SLOPE * vx;
        vy = vy > 0.f ? vy : NEG_SLOPE * vy;
        float p = vx * attv.x + vy * attv.y;
#pragma unroll
        for (int off = 32; off > 0; off >>= 1) p += __shfl_xor(p, off);
        if (p > m + RESCALE_THR) {
            float sc = __expf(m - p);
            accx *= sc; accy *= sc; denom *= sc;
            m = p;
        }
        float w = __expf(p - m);
        accx += w * x0.x;
        accy += w * x0.y;
        denom += w;
    }
#undef EPROJ
#undef DOTP

    // ---- self-loop (last): loop_attr projection = mean of eproj ----
    float invdeg = 1.f / fmaxf((float)cnt, 1.f);
    float sx = xli.x + xri.x + epsx * invdeg;
    float sy = xli.y + xri.y + epsy * invdeg;
    sx = sx > 0.f ? sx : NEG_SLOPE * sx;
    sy = sy > 0.f ? sy : NEG_SLOPE * sy;
    float ps = sx * attv.x + sy * attv.y;
#pragma unroll
    for (int off = 32; off > 0; off >>= 1) ps += __shfl_xor(ps, off);

    float mm = fmaxf(m, ps);
    float wf = __expf(m - mm);
    float ws = __expf(ps - mm);
    denom = denom * wf + ws;
    accx = accx * wf + ws * xli.x;
    accy = accy * wf + ws * xli.y;

    float ox = accx / denom + bov.x;
    float oy = accy / denom + bov.y;
    float2 o;
    o.x = ox / (1.f + __expf(-ox));
    o.y = oy / (1.f + __expf(-oy));
    ((float2*)(hout + (size_t)i * HIP_H))[t] = o;
}

// ---------------- host launch ----------------
extern "C" void kernel_launch(void* const* d_in, const int* in_sizes, int n_in,
                              void* d_out, int out_size, void* d_ws, size_t ws_size,
                              hipStream_t stream) {
    const float* x      = (const float*)d_in[0];
    const int*   ei     = (const int*)d_in[1];
    const float* ea     = (const float*)d_in[2];
    const float* W_emb  = (const float*)d_in[3];
    const float* b_emb  = (const float*)d_in[4];
    const float* Wl1    = (const float*)d_in[5];
    const float* bl1    = (const float*)d_in[6];
    const float* Wr1    = (const float*)d_in[7];
    const float* We1    = (const float*)d_in[8];
    const float* att1   = (const float*)d_in[9];
    const float* bo1    = (const float*)d_in[10];
    const float* Wl2    = (const float*)d_in[11];
    const float* bl2    = (const float*)d_in[12];
    const float* Wr2    = (const float*)d_in[13];
    const float* We2    = (const float*)d_in[14];
    const float* att2   = (const float*)d_in[15];
    const float* bo2    = (const float*)d_in[16];
    float* out = (float*)d_out;

    char* p = (char*)d_ws;
    auto carve = [&](size_t bytes) {
        void* q = (void*)p;
        p += (bytes + 255) / 256 * 256;
        return q;
    };
    float* h        = (float*)carve((size_t)HIP_N * 128 * 4);
    float* xl       = (float*)carve((size_t)HIP_N * 128 * 4);
    float* xr       = (float*)carve((size_t)HIP_N * 128 * 4);
    unsigned int* ea_h = (unsigned int*)carve((size_t)HIP_E * 16 * 4);
    int*   deg      = (int*)carve((size_t)HIP_N * 4);
    int*   offs     = (int*)carve((size_t)(HIP_N + 1) * 4);
    int*   cursor   = (int*)carve((size_t)HIP_N * 4);
    int*   e_src    = (int*)carve((size_t)HIP_E * 4);
    int*   flag     = (int*)carve(256);
    int*   bsums    = (int*)carve((size_t)SCAN_NB * 4);
    int*   bscan    = (int*)carve((size_t)SCAN_NB * 4);
    float* Wl1f     = (float*)carve(128 * 128 * 4);
    float* Wr1f     = (float*)carve(128 * 128 * 4);
    float* bl1f     = (float*)carve(128 * 4);
    float* br1f     = (float*)carve(128 * 4);
    float* zerob    = (float*)carve(128 * 4);
    unsigned int* Wepk1 = (unsigned int*)carve(2048 * 4);
    unsigned int* Wepk2 = (unsigned int*)carve(2048 * 4);

    hipMemsetAsync(deg, 0, (size_t)HIP_N * 4, stream);
    hipMemsetAsync(flag, 0, 4, stream);

    k_detect<<<16, 256, 0, stream>>>(ei, flag);
    k_hist<<<(HIP_E + 255) / 256, 256, 0, stream>>>(ei, flag, deg);
    k_scan1<<<SCAN_NB, 256, 0, stream>>>(deg, bsums);
    k_scan2<<<1, 64, 0, stream>>>(bsums, bscan);
    k_scan3<<<SCAN_NB, 1024, 0, stream>>>(deg, bscan, offs, cursor);
    k_compose<<<258, 128, 0, stream>>>(W_emb, b_emb, Wl1, bl1, Wr1,
                                       Wl1f, bl1f, Wr1f, br1f, zerob);
    k_packwe<<<16, 256, 0, stream>>>(We1, We2, Wepk1, Wepk2);

    // fat dispatch: layer-1 lin (composed weights, input x) + CSR scatter
    k_fat1<<<LINB + SCATB, 256, 0, stream>>>(x, Wl1f, bl1f, Wr1f, br1f, xl, xr,
                                             ei, flag, cursor, e_src, ea, ea_h);

    // ----- layer 1 -----
    k_node_fused<<<HIP_N, 64, 0, stream>>>(offs, e_src, ea_h, Wepk1, att1,
                                           xl, xr, bo1, h);
    // ----- layer 2 -----
    k_lin<<<(HIP_N + 31) / 32, 256, 0, stream>>>(h, Wl2, bl2, Wr2, zerob, xl, xr, HIP_N);
    k_node_fused<<<HIP_N, 64, 0, stream>>>(offs, e_src, ea_h, Wepk2, att2,
                                           xl, xr, bo2, out);
}